// Round 4
// baseline (497.556 us; speedup 1.0000x reference)
//
#include <hip/hip_runtime.h>
#include <math.h>

typedef float f32x4 __attribute__((ext_vector_type(4)));
typedef __bf16 bf16x8 __attribute__((ext_vector_type(8)));
typedef unsigned short u16x8 __attribute__((ext_vector_type(8)));
typedef unsigned short u16x4 __attribute__((ext_vector_type(4)));

#define LN2F_ 0.69314718055994530942f

__device__ inline unsigned short f2bf(float f) {
    unsigned u = __builtin_bit_cast(unsigned, f);
    u += 0x7fffu + ((u >> 16) & 1u);
    return (unsigned short)(u >> 16);
}

// ---------------------------------------------------------------------------
// Swizzled LDS tile, 16B blocks within 1 KiB stripes (16 rows x 32 bf16):
//   block(row,c) = (c<<4) + ((row&15) ^ (c<<1)), stripe = row>>4.
// frag_ld reads are conflict-free (verified by enumeration previously).
// Staging now uses global_load_lds with an INVERSE-swizzled global source:
// lane l of a wave writes LDS block l (HW: linear lane*16B), so lane l must
// fetch global (row = (l&15)^((l>>4)<<1), chunk = l>>4) of its stripe.
// XOR involution => identical layout to the old stage_st. [rule 21c / m201]
// ---------------------------------------------------------------------------
__device__ inline bf16x8 frag_ld(const unsigned short* Ls, int s, int ml, int q) {
    return __builtin_bit_cast(bf16x8,
        *(const u16x8*)(Ls + s * 512 + (((q) << 4) + (ml ^ ((q) << 1))) * 8));
}

__device__ inline void gll16(const unsigned short* g, unsigned short* l) {
    __builtin_amdgcn_global_load_lds(
        (const __attribute__((address_space(1))) unsigned int*)g,
        (__attribute__((address_space(3))) unsigned int*)l, 16, 0, 0);
}

// ---------------------------------------------------------------------------
// fp32 -> bf16 bulk convert (V: tiny; X: 134 MB -> 67 MB, ~33 us streaming)
// ---------------------------------------------------------------------------
__global__ __launch_bounds__(256) void k_cvt(const float* __restrict__ in,
                                             unsigned short* __restrict__ out, int n4) {
    int i = blockIdx.x * 256 + threadIdx.x;
    if (i >= n4) return;
    float4 v = ((const float4*)in)[i];
    u16x4 o = { f2bf(v.x), f2bf(v.y), f2bf(v.z), f2bf(v.w) };
    *(u16x4*)(out + (size_t)i * 4) = o;
}

// am[h][p][j] = bf16(alpha[h][(j - p) & 1023])
__global__ __launch_bounds__(256) void k_build_am(const float* __restrict__ alpha,
                                                  unsigned short* __restrict__ am) {
    int t = blockIdx.x * 256 + threadIdx.x;          // 0 .. 1048575
    int j8 = (t & 127) << 3;
    int p  = (t >> 7) & 1023;
    int h  = t >> 17;
    const float* ar = alpha + (h << 10);
    u16x8 o;
#pragma unroll
    for (int q = 0; q < 8; ++q) o[q] = f2bf(ar[(j8 + q - p) & 1023]);
    *(u16x8*)(am + ((size_t)t << 3)) = o;
}

// WT[e'][e] = bf16(W[e][e'])
__global__ __launch_bounds__(256) void k_build_wt(const float* __restrict__ W,
                                                  unsigned short* __restrict__ WT) {
    int t = blockIdx.x * 256 + threadIdx.x;          // 0 .. 262143
    int e1 = t >> 9, e = t & 511;
    WT[t] = f2bf(W[e * 512 + e1]);
}

// ---------------------------------------------------------------------------
// K1: wsT[n][e][p] = sum_d Xb[(n,p)][d] * Vb[e][d]   (A = pre-converted bf16)
//   BM=128, BN=128, BK=32; 4 waves x (64x64); global_load_lds staging.
//   XCD remap: 4 e-blocks per X panel co-XCD (kept from round 3 — fetch 4x down).
// ---------------------------------------------------------------------------
__global__ __launch_bounds__(256) void k_gemm1(const unsigned short* __restrict__ A,
                                               const unsigned short* __restrict__ B,
                                               unsigned short* __restrict__ wsT) {
    __shared__ __align__(16) unsigned short As[128 * 32];
    __shared__ __align__(16) unsigned short Bs[128 * 32];
    const int tid = threadIdx.x;
    const int flat = blockIdx.x;
    const int xcd = flat & 7, slot = flat >> 3;
    const int m0 = (xcd * 64 + (slot >> 2)) * 128;
    const int e0 = (slot & 3) * 128;
    const int w = tid >> 6, lane = tid & 63, ml = lane & 15, quad = lane >> 4;
    const int wr = w >> 1, wc = w & 1;
    const int srl = (lane & 15) ^ ((lane >> 4) << 1);   // inverse-swizzled row
    const int scl = lane >> 4;                          // chunk
    const unsigned short* pA0 = A + (size_t)(m0 + w * 32 + srl) * 512 + scl * 8;
    const unsigned short* pA1 = pA0 + 16 * 512;
    const unsigned short* pB0 = B + (size_t)(e0 + w * 32 + srl) * 512 + scl * 8;
    const unsigned short* pB1 = pB0 + 16 * 512;
    unsigned short* lA0 = As + w * 1024;
    unsigned short* lA1 = lA0 + 512;
    unsigned short* lB0 = Bs + w * 1024;
    unsigned short* lB1 = lB0 + 512;
    f32x4 acc[4][4] = {};
    for (int k0 = 0; k0 < 512; k0 += 32) {
        __syncthreads();
        gll16(pA0 + k0, lA0);
        gll16(pA1 + k0, lA1);
        gll16(pB0 + k0, lB0);
        gll16(pB1 + k0, lB1);
        __syncthreads();
        bf16x8 af[4], bfr[4];
#pragma unroll
        for (int i = 0; i < 4; ++i) {
            af[i]  = frag_ld(As, wr * 4 + i, ml, quad);
            bfr[i] = frag_ld(Bs, wc * 4 + i, ml, quad);
        }
#pragma unroll
        for (int i = 0; i < 4; ++i)
#pragma unroll
            for (int j = 0; j < 4; ++j)
                acc[i][j] = __builtin_amdgcn_mfma_f32_16x16x32_bf16(af[i], bfr[j], acc[i][j], 0, 0, 0);
    }
    const int n = m0 >> 10;
    const int pblk = m0 & 1023;
#pragma unroll
    for (int i = 0; i < 4; ++i) {
        int p = pblk + wr * 64 + i * 16 + quad * 4;
#pragma unroll
        for (int j = 0; j < 4; ++j) {
            int e = e0 + wc * 64 + j * 16 + ml;
            u16x4 o = { f2bf(acc[i][j][0]), f2bf(acc[i][j][1]),
                        f2bf(acc[i][j][2]), f2bf(acc[i][j][3]) };
            *(u16x4*)(wsT + ((size_t)n * 512 + e) * 1024 + p) = o;
        }
    }
}

// ---------------------------------------------------------------------------
// K2: y[n][p][h*64+r] = sum_j am[h][p][j] * wsT[n][h*64+r][j]
//   n-batched 4; 512 threads = 8 waves = (4 n) x (2 p-halves).
//   global_load_lds staging: per wave 2 A-stripes + 1 B-stripe.
//   XCD remap: 8 p-blocks per wsT A-panel co-XCD (kept from round 3).
// ---------------------------------------------------------------------------
__global__ __launch_bounds__(512) void k_gemm2(const unsigned short* __restrict__ wsT,
                                               const unsigned short* __restrict__ am,
                                               unsigned short* __restrict__ y) {
    __shared__ __align__(16) unsigned short As[256 * 32];   // stripes 0..15
    __shared__ __align__(16) unsigned short Bs[128 * 32];   // stripes 0..7
    const int tid = threadIdx.x;
    const int flat = blockIdx.x;
    const int xcd = flat & 7, slot = flat >> 3;
    const int panel = xcd * 16 + (slot >> 3);
    const int p0 = (slot & 7) * 128;
    const int h  = panel & 7;
    const int n0 = (panel >> 3) * 4;
    const int w = tid >> 6, lane = tid & 63, ml = lane & 15, quad = lane >> 4;
    const int wn = w >> 1, wp = w & 1;
    const int srl = (lane & 15) ^ ((lane >> 4) << 1);
    const int scl = lane >> 4;
    // A stripes 2w, 2w+1: stripe st -> n = n0 + (st>>2), r = (st&3)*16 + srl
    const unsigned short* pA0 = wsT + (size_t)(n0 + (w >> 1)) * 524288
        + (size_t)(h * 64 + ((2 * w) & 3) * 16 + srl) * 1024 + scl * 8;
    const unsigned short* pA1 = wsT + (size_t)(n0 + (w >> 1)) * 524288
        + (size_t)(h * 64 + ((2 * w + 1) & 3) * 16 + srl) * 1024 + scl * 8;
    // B stripe w: rows p0 + w*16 + srl
    const unsigned short* pB = am + ((size_t)h * 1024 + p0 + w * 16 + srl) * 1024 + scl * 8;
    unsigned short* lA0 = As + (2 * w) * 512;
    unsigned short* lA1 = lA0 + 512;
    unsigned short* lB  = Bs + w * 512;
    f32x4 acc[4][4] = {};
    for (int j0 = 0; j0 < 1024; j0 += 32) {
        __syncthreads();
        gll16(pA0 + j0, lA0);
        gll16(pA1 + j0, lA1);
        gll16(pB + j0, lB);
        __syncthreads();
        bf16x8 af[4], bfr[4];
#pragma unroll
        for (int mt = 0; mt < 4; ++mt)
            af[mt] = frag_ld(As, wn * 4 + mt, ml, quad);
#pragma unroll
        for (int nt = 0; nt < 4; ++nt)
            bfr[nt] = frag_ld(Bs, wp * 4 + nt, ml, quad);
#pragma unroll
        for (int mt = 0; mt < 4; ++mt)
#pragma unroll
            for (int nt = 0; nt < 4; ++nt)
                acc[mt][nt] = __builtin_amdgcn_mfma_f32_16x16x32_bf16(af[mt], bfr[nt], acc[mt][nt], 0, 0, 0);
    }
    const int n = n0 + wn;
#pragma unroll
    for (int mt = 0; mt < 4; ++mt) {
        int r0 = mt * 16 + quad * 4;
#pragma unroll
        for (int nt = 0; nt < 4; ++nt) {
            int p = p0 + wp * 64 + nt * 16 + ml;
            u16x4 o = { f2bf(acc[mt][nt][0]), f2bf(acc[mt][nt][1]),
                        f2bf(acc[mt][nt][2]), f2bf(acc[mt][nt][3]) };
            *(u16x4*)(y + ((size_t)n * 1024 + p) * 512 + h * 64 + r0) = o;
        }
    }
}

// ---------------------------------------------------------------------------
// K3: out[m][e'] = log_cosh( sum_e y[m][e] * WT[e'][e] + b[e'] )  (fp32 out)
//   Same structure as K1; logcosh epilogue via __expf/__logf.
// ---------------------------------------------------------------------------
__global__ __launch_bounds__(256) void k_gemm3(const unsigned short* __restrict__ A,
                                               const unsigned short* __restrict__ B,
                                               const float* __restrict__ bias,
                                               float* __restrict__ out) {
    __shared__ __align__(16) unsigned short As[128 * 32];
    __shared__ __align__(16) unsigned short Bs[128 * 32];
    const int tid = threadIdx.x;
    const int flat = blockIdx.x;
    const int xcd = flat & 7, slot = flat >> 3;
    const int m0 = (xcd * 64 + (slot >> 2)) * 128;
    const int e0 = (slot & 3) * 128;
    const int w = tid >> 6, lane = tid & 63, ml = lane & 15, quad = lane >> 4;
    const int wr = w >> 1, wc = w & 1;
    const int srl = (lane & 15) ^ ((lane >> 4) << 1);
    const int scl = lane >> 4;
    const unsigned short* pA0 = A + (size_t)(m0 + w * 32 + srl) * 512 + scl * 8;
    const unsigned short* pA1 = pA0 + 16 * 512;
    const unsigned short* pB0 = B + (size_t)(e0 + w * 32 + srl) * 512 + scl * 8;
    const unsigned short* pB1 = pB0 + 16 * 512;
    unsigned short* lA0 = As + w * 1024;
    unsigned short* lA1 = lA0 + 512;
    unsigned short* lB0 = Bs + w * 1024;
    unsigned short* lB1 = lB0 + 512;
    f32x4 acc[4][4] = {};
    for (int k0 = 0; k0 < 512; k0 += 32) {
        __syncthreads();
        gll16(pA0 + k0, lA0);
        gll16(pA1 + k0, lA1);
        gll16(pB0 + k0, lB0);
        gll16(pB1 + k0, lB1);
        __syncthreads();
        bf16x8 af[4], bfr[4];
#pragma unroll
        for (int i = 0; i < 4; ++i) {
            af[i]  = frag_ld(As, wr * 4 + i, ml, quad);
            bfr[i] = frag_ld(Bs, wc * 4 + i, ml, quad);
        }
#pragma unroll
        for (int i = 0; i < 4; ++i)
#pragma unroll
            for (int j = 0; j < 4; ++j)
                acc[i][j] = __builtin_amdgcn_mfma_f32_16x16x32_bf16(af[i], bfr[j], acc[i][j], 0, 0, 0);
    }
#pragma unroll
    for (int j = 0; j < 4; ++j) {
        int e = e0 + wc * 64 + j * 16 + ml;
        float bv = bias[e];
#pragma unroll
        for (int i = 0; i < 4; ++i) {
            int mg = m0 + wr * 64 + i * 16 + quad * 4;
#pragma unroll
            for (int r = 0; r < 4; ++r) {
                float v  = acc[i][j][r] + bv;
                float ax = fabsf(v);
                float t  = __expf(-2.0f * ax);
                out[(size_t)(mg + r) * 512 + e] = ax + __logf(1.0f + t) - LN2F_;
            }
        }
    }
}

// ---------------------------------------------------------------------------
// Buffers:
//   d_out (134 MB): [am 16.8 MB | Vb 0.5 MB | Xb 67 MB]  (all consumed before
//                    K3 writes `out` over the region)
//   d_ws  (134 MB): [wsT 67 MB (reused for WT after K2) | y 67 MB]
// Order: cvt(V), cvt(X), build_am -> K1 -> K2 -> build_wt -> K3
// ---------------------------------------------------------------------------
extern "C" void kernel_launch(void* const* d_in, const int* in_sizes, int n_in,
                              void* d_out, int out_size, void* d_ws, size_t ws_size,
                              hipStream_t stream) {
    const float* x     = (const float*)d_in[0];
    const float* alpha = (const float*)d_in[1];
    const float* V     = (const float*)d_in[2];
    const float* W     = (const float*)d_in[3];
    const float* b     = (const float*)d_in[4];

    unsigned short* am  = (unsigned short*)d_out;
    unsigned short* Vb  = am + 8388608;
    unsigned short* Xb  = Vb + 262144;
    unsigned short* wsT = (unsigned short*)d_ws;
    unsigned short* y   = wsT + 33554432;
    unsigned short* WT  = wsT;
    float* out = (float*)d_out;

    k_cvt<<<256, 256, 0, stream>>>(V, Vb, 65536);
    k_cvt<<<32768, 256, 0, stream>>>(x, Xb, 8388608);
    k_build_am<<<4096, 256, 0, stream>>>(alpha, am);

    k_gemm1<<<dim3(2048), 256, 0, stream>>>(Xb, Vb, wsT);
    k_gemm2<<<dim3(1024), 512, 0, stream>>>(wsT, am, y);
    k_build_wt<<<1024, 256, 0, stream>>>(W, WT);
    k_gemm3<<<dim3(2048), 256, 0, stream>>>(y, WT, b, out);
}